// Round 7
// baseline (593.763 us; speedup 1.0000x reference)
//
#include <hip/hip_runtime.h>

typedef unsigned short u16;
typedef __attribute__((ext_vector_type(8))) short short8;
typedef __attribute__((ext_vector_type(4))) float float4v;

#define MFMA_BF16(a, b, c) __builtin_amdgcn_mfma_f32_16x16x32_bf16((a), (b), (c), 0, 0, 0)

#define B_ 4
#define S_ 2048
#define D_ 1024
#define H_ 8
#define DH_ 128
#define DFF_ 4096
#define EPS_ 1e-5f
#define ROWS_ (B_ * S_)   // 8192
#define CSCALE_ 0.12751672939502f  // (1/sqrt(128)) * log2(e), folded into Q

__device__ __forceinline__ u16 f2bf(float f) {
  union { float f; unsigned u; } x; x.f = f;
  unsigned r = x.u + 0x7fffu + ((x.u >> 16) & 1u);
  return (u16)(r >> 16);
}

typedef __attribute__((address_space(1))) const unsigned int guint;
typedef __attribute__((address_space(3))) unsigned int luint;
__device__ __forceinline__ void gl2lds16(const u16* g, u16* l) {
  // each lane: 16B from its own g -> wave-uniform lds base + lane*16
  __builtin_amdgcn_global_load_lds((guint*)g, (luint*)l, 16, 0, 0);
}

// Tiled fragment-major layout for GEMM *A* operands: (row, k) lives in 128x32
// tiles, each tile 4096 elems (8 KB) contiguous. A wave's A-fragment load is
// then ONE coalesced 1 KB global_load_dwordx4 straight to registers.
__device__ __forceinline__ size_t tiled_off(int row, int k, int Kdim) {
  return ((size_t)(row >> 7) * (Kdim >> 5) + (k >> 5)) * 4096 +
         (size_t)((row & 127) << 5) + (k & 31);
}

// ---------------- cast fp32 row-major -> bf16 tiled (src) ----------------
__global__ void cast_tiled_kernel(const float* __restrict__ in, u16* __restrict__ out) {
  int idx = blockIdx.x * 256 + threadIdx.x;
  int g = idx * 4;
  int m = g >> 10, k = g & 1023;  // D_ = 1024
  float4 v = *(const float4*)(in + (size_t)g);
  ushort4 u;
  u.x = f2bf(v.x); u.y = f2bf(v.y); u.z = f2bf(v.z); u.w = f2bf(v.w);
  *(ushort4*)(out + tiled_off(m, k, D_)) = u;
}

// ---- all 4 weight transposes in ONE launch: fp32 [K][N] -> bf16 [N][K] ----
__global__ void transpose_cast4_kernel(
    const float* __restrict__ w_qkv, const float* __restrict__ w_out,
    const float* __restrict__ w1, const float* __restrict__ w2,
    u16* __restrict__ o_qkv, u16* __restrict__ o_out,
    u16* __restrict__ o_w1, u16* __restrict__ o_w2) {
  __shared__ float t[32][33];
  int id = blockIdx.x;
  const float* in; u16* out; int K, N, bx, by;
  if (id < 3072)      { in = w_qkv; out = o_qkv; K = 1024; N = 3072; bx = id & 31;  by = id >> 5; }
  else if (id < 4096) { id -= 3072; in = w_out; out = o_out; K = 1024; N = 1024; bx = id & 31;  by = id >> 5; }
  else if (id < 8192) { id -= 4096; in = w1;    out = o_w1;  K = 1024; N = 4096; bx = id & 31;  by = id >> 5; }
  else                { id -= 8192; in = w2;    out = o_w2;  K = 4096; N = 1024; bx = id & 127; by = id >> 7; }
  const int k0 = bx * 32, n0 = by * 32;
  const int tx = threadIdx.x & 31, ty = threadIdx.x >> 5;  // 32x8 threads
  #pragma unroll
  for (int i = 0; i < 4; ++i)
    t[ty + 8 * i][tx] = in[(size_t)(k0 + ty + 8 * i) * N + n0 + tx];
  __syncthreads();
  #pragma unroll
  for (int i = 0; i < 4; ++i)
    out[(size_t)(n0 + ty + 8 * i) * K + k0 + tx] = f2bf(t[tx][ty + 8 * i]);
}

// ---- bf16 MFMA GEMM v7 (hybrid, BK=64): C[M,N] = A[M,K] @ Bt[N,K]^T ----
// A TILED global -> registers (full register dbuf, coalesced 1 KB loads).
// B row-major -> LDS via global_load_lds, double-buffered, ONE barrier per
// 64-K iter (half the barrier-drain events of BK=32). B buffer is 2 stacked
// [128][32] half-slabs so DMA dest stays lane-contiguous and fragment
// ds_read_b128 geometry matches the known-good BK=32 pattern.
// Grid is 1-D, XCD-partition swizzled: bid&7 selects an n-slice so each XCD's
// private L2 keeps its own <=1 MB slice of B resident (perf heuristic only).
// MODE 0: q/k scatter [b,h,s,dh] (q pre-scaled), V written DIRECTLY as
// [bh][dh][s] packed 8B stores (transpose folded in); MODE 1: +resid fp32;
// MODE 2: +bias relu bf16 TILED; MODE 3: +bias+resid fp32.
template <int MODE, int KT>
__global__ __launch_bounds__(256) void gemm_kernel(
    const u16* __restrict__ A, const u16* __restrict__ Bt, const int nTiles,
    float* __restrict__ outF, u16* __restrict__ outH, const float* __restrict__ bias,
    const float* __restrict__ resid,
    u16* __restrict__ qo, u16* __restrict__ ko, u16* __restrict__ vTo) {
  __shared__ u16 Bs[2][2][128][32];  // [buf][k-half][n][32k] = 32 KB
  const int tid = threadIdx.x;
  const int lane = tid & 63, wave = tid >> 6;
  const int quad = lane >> 4, r16 = lane & 15;
  const int wm = (wave >> 1) * 64, wn = (wave & 1) * 64;
  // XCD-partitioned swizzle (M is always 8192 -> 64 m-tiles)
  const int bid = blockIdx.x;
  const int xcd = bid & 7, loc = bid >> 3;
  const int nPerX = nTiles >> 3;
  const int m0 = (loc & 63) * 128;
  const int n0 = (xcd * nPerX + (loc >> 6)) * 128;
  const int N = nTiles << 7;
  constexpr int K = KT, niter = KT >> 6;

  float4v acc[4][4];
  #pragma unroll
  for (int i = 0; i < 4; ++i)
    #pragma unroll
    for (int j = 0; j < 4; ++j) acc[i][j] = (float4v)0.0f;

  // B DMA: 4 instrs/iter/wave; instr (h,g): 16 rows x 32 k, 1 KB contiguous.
  const int srow = lane >> 2, sseg = lane & 3;
  const u16* Bg[4];
  u16* Bl[4];
  #pragma unroll
  for (int h = 0; h < 2; ++h)
    #pragma unroll
    for (int g2 = 0; g2 < 2; ++g2) {
      Bg[h * 2 + g2] = Bt + (size_t)(n0 + wave * 32 + 16 * g2 + srow) * K + h * 32 + sseg * 8;
      Bl[h * 2 + g2] = &Bs[0][h][wave * 32 + 16 * g2][0];
    }
  constexpr int bufStep = 2 * 128 * 32;  // u16 elems per buffer

  // A fragment pointers (tiled): rows wm + t*16 + r16, k seg quad*8
  const u16* ap[4];
  #pragma unroll
  for (int t = 0; t < 4; ++t)
    ap[t] = A + (size_t)(m0 >> 7) * (K >> 5) * 4096 +
            (size_t)((wm + t * 16 + r16) << 5) + quad * 8;

  // prologue: B tile 0 -> buf 0; A frags (2 k-halves) -> registers
  #pragma unroll
  for (int e = 0; e < 4; ++e) gl2lds16(Bg[e], Bl[e]);
  short8 a_cur[8], a_nxt[8];
  #pragma unroll
  for (int t = 0; t < 4; ++t)
    #pragma unroll
    for (int h2 = 0; h2 < 2; ++h2)
      a_cur[t * 2 + h2] = *(const short8*)(ap[t] + h2 * 4096);

  #pragma unroll 2
  for (int i = 0; i < niter; ++i) {
    __syncthreads();  // drains B-DMA(i) (in flight one full iter) + last A prefetch
    if (i + 1 < niter) {
      const size_t kb = (size_t)(i + 1) * 64;
      const int bo = ((i + 1) & 1) ? bufStep : 0;
      #pragma unroll
      for (int e = 0; e < 4; ++e) gl2lds16(Bg[e] + kb, Bl[e] + bo);
      const size_t to = (size_t)(i + 1) * 2 * 4096;
      #pragma unroll
      for (int t = 0; t < 4; ++t)
        #pragma unroll
        for (int h2 = 0; h2 < 2; ++h2)
          a_nxt[t * 2 + h2] = *(const short8*)(ap[t] + to + h2 * 4096);
    }
    const u16* bb = &Bs[i & 1][0][0][0];
    short8 bf0[4], bf1[4];
    #pragma unroll
    for (int t = 0; t < 4; ++t)
      bf0[t] = *(const short8*)(bb + ((wn + t * 16 + r16) << 5) + quad * 8);
    #pragma unroll
    for (int t = 0; t < 4; ++t)
      bf1[t] = *(const short8*)(bb + 128 * 32 + ((wn + t * 16 + r16) << 5) + quad * 8);
    #pragma unroll
    for (int ii = 0; ii < 4; ++ii)
      #pragma unroll
      for (int j = 0; j < 4; ++j) acc[ii][j] = MFMA_BF16(a_cur[ii * 2], bf0[j], acc[ii][j]);
    #pragma unroll
    for (int ii = 0; ii < 4; ++ii)
      #pragma unroll
      for (int j = 0; j < 4; ++j) acc[ii][j] = MFMA_BF16(a_cur[ii * 2 + 1], bf1[j], acc[ii][j]);
    #pragma unroll
    for (int e = 0; e < 8; ++e) a_cur[e] = a_nxt[e];
  }

  // epilogue: D row = quad*4+reg, col = r16 within each 16x16 tile
  #pragma unroll
  for (int i = 0; i < 4; ++i) {
    const int rowb = m0 + wm + i * 16 + quad * 4;
    #pragma unroll
    for (int j = 0; j < 4; ++j) {
      const int col = n0 + wn + j * 16 + r16;
      if (MODE == 0) {
        const int part = col >> 10, cc = col & 1023;
        const int h = cc >> 7, dh = cc & 127;
        const int b = rowb >> 11, s = rowb & 2047;  // rows rowb..rowb+3 same b
        if (part == 2) {
          // V directly transposed: [bh][dh][s], 4 s-consecutive -> 8B store
          ushort4 pk;
          pk.x = f2bf(acc[i][j][0]); pk.y = f2bf(acc[i][j][1]);
          pk.z = f2bf(acc[i][j][2]); pk.w = f2bf(acc[i][j][3]);
          *(ushort4*)&vTo[((size_t)(b * H_ + h) * DH_ + dh) * S_ + s] = pk;
        } else {
          u16* dst = (part == 0) ? qo : ko;
          #pragma unroll
          for (int rg = 0; rg < 4; ++rg) {
            float val = acc[i][j][rg];
            if (part == 0) val *= CSCALE_;  // fold softmax scale*log2e into Q
            dst[((size_t)(b * H_ + h) * S_ + s + rg) * DH_ + dh] = f2bf(val);
          }
        }
      } else {
        #pragma unroll
        for (int rg = 0; rg < 4; ++rg) {
          float val = acc[i][j][rg];
          const int r = rowb + rg;
          if (MODE == 1) {
            val += resid[(size_t)r * N + col];  // + src residual
            outF[(size_t)r * N + col] = val;
          } else if (MODE == 2) {
            val += bias[col];
            val = fmaxf(val, 0.0f);
            outH[tiled_off(r, col, N)] = f2bf(val);  // tiled: feeds FFN2 A
          } else {
            val += bias[col] + resid[(size_t)r * N + col];  // + xf residual
            outF[(size_t)r * N + col] = val;
          }
        }
      }
    }
  }
}

// ---------------- flash causal attention (S^T formulation) ----------------
// O written TILED (feeds proj GEMM as A operand).
__global__ __launch_bounds__(256) void attn_kernel(
    const u16* __restrict__ Q, const u16* __restrict__ Kg,
    const u16* __restrict__ Vtg, u16* __restrict__ O) {
  __shared__ u16 Ks[64][136];     // [key][d]
  __shared__ u16 Vt[128][72];     // [d][key]
  __shared__ u16 Pw[4][16][72];   // per-wave P [q][key]
  const int tid = threadIdx.x;
  const int lane = tid & 63, wave = tid >> 6;
  const int quad = lane >> 4, r16 = lane & 15;
  const int pairIdx = blockIdx.x;  // 0..15
  const int bh = blockIdx.y;       // 0..31
  const size_t base = (size_t)bh * S_ * DH_;
  const size_t vtb = (size_t)bh * DH_ * S_;
  const int b = bh >> 3, h = bh & 7;

  const u16* kg0 = Kg + base + (size_t)(tid >> 4) * DH_ + (tid & 15) * 8;
  u16* ksl = &Ks[tid >> 4][(tid & 15) * 8];
  const u16* vg0 = Vtg + vtb + (size_t)(tid >> 3) * S_ + (tid & 7) * 8;
  u16* vtl = &Vt[tid >> 3][(tid & 7) * 8];

  for (int half = 0; half < 2; ++half) {
    const int qb = (half == 0) ? pairIdx : 31 - pairIdx;
    const int qr = qb * 64 + wave * 16 + r16;

    short8 aq[4];
    #pragma unroll
    for (int ks = 0; ks < 4; ++ks)
      aq[ks] = *(const short8*)(Q + base + (size_t)qr * DH_ + ks * 32 + quad * 8);

    float4v acco[8];
    #pragma unroll
    for (int i = 0; i < 8; ++i) acco[i] = (float4v)0.0f;
    float m_q = -1e30f, l_q = 0.0f;

    for (int kb = 0; kb <= qb; ++kb) {
      __syncthreads();
      #pragma unroll
      for (int i = 0; i < 4; ++i)
        *(short8*)(ksl + i * 16 * 136) =
            *(const short8*)(kg0 + (size_t)(kb * 64 + i * 16) * DH_);
      #pragma unroll
      for (int i = 0; i < 4; ++i)
        *(short8*)(vtl + i * 32 * 72) =
            *(const short8*)(vg0 + (size_t)i * 32 * S_ + kb * 64);
      __syncthreads();

      float4v accs[4];
      #pragma unroll
      for (int t = 0; t < 4; ++t) accs[t] = (float4v)0.0f;
      #pragma unroll
      for (int ks = 0; ks < 4; ++ks) {
        #pragma unroll
        for (int t = 0; t < 4; ++t) {
          short8 ak = *(const short8*)&Ks[t * 16 + r16][ks * 32 + quad * 8];
          accs[t] = MFMA_BF16(ak, aq[ks], accs[t]);
        }
      }
      if (kb == qb) {
        #pragma unroll
        for (int t = 0; t < 4; ++t)
          #pragma unroll
          for (int rg = 0; rg < 4; ++rg) {
            int kc = kb * 64 + t * 16 + quad * 4 + rg;
            if (kc > qr) accs[t][rg] = -1e30f;
          }
      }
      float mv = accs[0][0];
      #pragma unroll
      for (int t = 0; t < 4; ++t)
        #pragma unroll
        for (int rg = 0; rg < 4; ++rg) mv = fmaxf(mv, accs[t][rg]);
      mv = fmaxf(mv, __shfl_xor(mv, 16));
      mv = fmaxf(mv, __shfl_xor(mv, 32));
      const float mnew = fmaxf(m_q, mv);
      const float alpha = __builtin_amdgcn_exp2f(m_q - mnew);
      float s0 = 0.0f;
      #pragma unroll
      for (int t = 0; t < 4; ++t)
        #pragma unroll
        for (int rg = 0; rg < 4; ++rg) {
          float p = __builtin_amdgcn_exp2f(accs[t][rg] - mnew);
          accs[t][rg] = p;
          s0 += p;
        }
      s0 += __shfl_xor(s0, 16);
      s0 += __shfl_xor(s0, 32);
      l_q = l_q * alpha + s0;
      m_q = mnew;

      #pragma unroll
      for (int t = 0; t < 4; ++t) {
        union { float f; unsigned u; } c0, c1, c2, c3;
        c0.f = accs[t][0]; c1.f = accs[t][1]; c2.f = accs[t][2]; c3.f = accs[t][3];
        uint2 pk;
        pk.x = ((c0.u + 0x8000u) >> 16) | ((c1.u + 0x8000u) & 0xffff0000u);
        pk.y = ((c2.u + 0x8000u) >> 16) | ((c3.u + 0x8000u) & 0xffff0000u);
        *(uint2*)&Pw[wave][r16][t * 16 + quad * 4] = pk;
      }
      float al[4];
      #pragma unroll
      for (int rg = 0; rg < 4; ++rg) al[rg] = __shfl(alpha, quad * 4 + rg);
      #pragma unroll
      for (int nt = 0; nt < 8; ++nt)
        #pragma unroll
        for (int rg = 0; rg < 4; ++rg) acco[nt][rg] *= al[rg];
      asm volatile("s_waitcnt lgkmcnt(0)" ::: "memory");
      #pragma unroll
      for (int ks2 = 0; ks2 < 2; ++ks2) {
        short8 ap = *(const short8*)&Pw[wave][r16][ks2 * 32 + quad * 8];
        #pragma unroll
        for (int nt = 0; nt < 8; ++nt) {
          short8 bv = *(const short8*)&Vt[nt * 16 + r16][ks2 * 32 + quad * 8];
          acco[nt] = MFMA_BF16(ap, bv, acco[nt]);
        }
      }
    }

    float lr[4];
    #pragma unroll
    for (int rg = 0; rg < 4; ++rg) lr[rg] = __shfl(l_q, quad * 4 + rg);
    const int sbase = qb * 64 + wave * 16 + quad * 4;
    #pragma unroll
    for (int nt = 0; nt < 8; ++nt)
      #pragma unroll
      for (int rg = 0; rg < 4; ++rg) {
        float val = acco[nt][rg] / lr[rg];
        const int row = b * S_ + sbase + rg;
        const int col = h * DH_ + nt * 16 + r16;
        O[tiled_off(row, col, D_)] = f2bf(val);  // tiled: feeds proj GEMM A
      }
  }
}

// ---------------- layernorm: y = LN(a) * g + be ----------------
// xf row-major fp32 (residual path); xb TILED bf16 (feeds FFN1 as A).
__global__ __launch_bounds__(256) void ln_kernel(
    const float* __restrict__ a,
    const float* __restrict__ g, const float* __restrict__ be,
    float* __restrict__ xf, u16* __restrict__ xb) {
  __shared__ float red[8];
  const int row = blockIdx.x, tid = threadIdx.x;
  float4 v = ((const float4*)(a + (size_t)row * D_))[tid];
  float s = v.x + v.y + v.z + v.w;
  float q = v.x * v.x + v.y * v.y + v.z * v.z + v.w * v.w;
  #pragma unroll
  for (int m = 1; m < 64; m <<= 1) {
    s += __shfl_xor(s, m);
    q += __shfl_xor(q, m);
  }
  const int wave = tid >> 6, lane = tid & 63;
  if (lane == 0) { red[wave] = s; red[4 + wave] = q; }
  __syncthreads();
  s = red[0] + red[1] + red[2] + red[3];
  q = red[4] + red[5] + red[6] + red[7];
  const float mu = s * (1.0f / D_);
  const float var = q * (1.0f / D_) - mu * mu;
  const float inv = rsqrtf(var + EPS_);
  const float4 gg = ((const float4*)g)[tid];
  const float4 bb = ((const float4*)be)[tid];
  float4 y;
  y.x = (v.x - mu) * inv * gg.x + bb.x;
  y.y = (v.y - mu) * inv * gg.y + bb.y;
  y.z = (v.z - mu) * inv * gg.z + bb.z;
  y.w = (v.w - mu) * inv * gg.w + bb.w;
  if (xf) ((float4*)(xf + (size_t)row * D_))[tid] = y;
  if (xb) {
    ushort4 u;
    u.x = f2bf(y.x); u.y = f2bf(y.y); u.z = f2bf(y.z); u.w = f2bf(y.w);
    *(ushort4*)(xb + tiled_off(row, tid * 4, D_)) = u;
  }
}

extern "C" void kernel_launch(void* const* d_in, const int* in_sizes, int n_in,
                              void* d_out, int out_size, void* d_ws, size_t ws_size,
                              hipStream_t stream) {
  const float* src   = (const float*)d_in[0];
  const float* w_qkv = (const float*)d_in[1];
  const float* w_out = (const float*)d_in[2];
  const float* w1    = (const float*)d_in[3];
  const float* b1    = (const float*)d_in[4];
  const float* w2    = (const float*)d_in[5];
  const float* b2    = (const float*)d_in[6];
  const float* g1    = (const float*)d_in[7];
  const float* be1   = (const float*)d_in[8];
  const float* g2    = (const float*)d_in[9];
  const float* be2   = (const float*)d_in[10];
  float* out = (float*)d_out;

  char* ws = (char*)d_ws;
  size_t off = 0;
  auto alloc = [&](size_t bytes) -> void* {
    void* p = ws + off;
    off += (bytes + 255) & ~(size_t)255;
    return p;
  };
  u16* src_bf = (u16*)alloc((size_t)ROWS_ * D_ * 2);    // TILED (A of qkv GEMM)
  u16* wqkvT  = (u16*)alloc((size_t)3 * D_ * D_ * 2);   // row-major [3072][1024]
  u16* woutT  = (u16*)alloc((size_t)D_ * D_ * 2);       // row-major [1024][1024]
  u16* w1T    = (u16*)alloc((size_t)DFF_ * D_ * 2);     // row-major [4096][1024]
  u16* w2T    = (u16*)alloc((size_t)D_ * DFF_ * 2);     // row-major [1024][4096]
  u16* qbuf   = (u16*)alloc((size_t)ROWS_ * D_ * 2);    // [b,h,s,dh]
  u16* kbuf   = (u16*)alloc((size_t)ROWS_ * D_ * 2);    // [b,h,s,dh]
  u16* vT     = (u16*)alloc((size_t)ROWS_ * D_ * 2);    // [b,h,dh,s] (from qkv epilogue)
  u16* obuf   = (u16*)alloc((size_t)ROWS_ * D_ * 2);    // TILED (A of proj GEMM)
  float* proj = (float*)alloc((size_t)ROWS_ * D_ * 4);  // row-major fp32
  float* xf   = (float*)alloc((size_t)ROWS_ * D_ * 4);  // row-major fp32
  u16* xb     = (u16*)alloc((size_t)ROWS_ * D_ * 2);    // TILED (A of FFN1)
  u16* h1     = qbuf;   // alias: q,k,vT,o dead before FFN1 writes (TILED, 64MB)
  float* ff   = proj;   // alias: proj dead after LN1

  cast_tiled_kernel<<<ROWS_ * D_ / 4 / 256, 256, 0, stream>>>(src, src_bf);
  transpose_cast4_kernel<<<12288, 256, 0, stream>>>(w_qkv, w_out, w1, w2,
                                                    wqkvT, woutT, w1T, w2T);

  // qkv = src @ w_qkv -> q,k [b,h,s,dh]; V directly as [b,h,dh,s]
  gemm_kernel<0, 1024><<<1536, 256, 0, stream>>>(
      src_bf, wqkvT, 24, nullptr, nullptr, nullptr, nullptr, qbuf, kbuf, vT);
  attn_kernel<<<dim3(16, B_ * H_), 256, 0, stream>>>(qbuf, kbuf, vT, obuf);
  // proj = o @ w_out + src (residual fused)
  gemm_kernel<1, 1024><<<512, 256, 0, stream>>>(
      obuf, woutT, 8, proj, nullptr, nullptr, src, nullptr, nullptr, nullptr);
  // x = LN(proj) -> xf fp32 row-major, xb bf16 tiled
  ln_kernel<<<ROWS_, 256, 0, stream>>>(proj, g1, be1, xf, xb);
  // h1 = relu(x @ w1 + b1) (bf16, tiled out)
  gemm_kernel<2, 1024><<<2048, 256, 0, stream>>>(
      xb, w1T, 32, nullptr, h1, b1, nullptr, nullptr, nullptr, nullptr);
  // ff = h1 @ w2 + b2 + xf (residual fused)
  gemm_kernel<3, 4096><<<512, 256, 0, stream>>>(
      h1, w2T, 8, ff, nullptr, b2, xf, nullptr, nullptr, nullptr);
  // out = LN(ff)
  ln_kernel<<<ROWS_, 256, 0, stream>>>(ff, g2, be2, out, nullptr);
}